// Round 7
// baseline (630.782 us; speedup 1.0000x reference)
//
#include <hip/hip_runtime.h>

typedef __bf16 bf16;
typedef __bf16 bf16x4 __attribute__((ext_vector_type(4)));
typedef __bf16 bf16x8 __attribute__((ext_vector_type(8)));
typedef float f32x4 __attribute__((ext_vector_type(4)));

#define S_LEN 2048
#define HID   3584
#define NHEADS 16
#define NKVH   8
#define HDIM   256
#define QKV_O  8192   // (16 + 2*8) * 256
#define O_IN   4096   // 16 * 256

typedef const __attribute__((address_space(1))) void* gp_t;
typedef __attribute__((address_space(3))) void* sp_t;

__device__ __forceinline__ void async16(const void* g, void* s) {
  __builtin_amdgcn_global_load_lds((gp_t)g, (sp_t)s, 16, 0, 0);
}

__device__ __forceinline__ f32x4 mfma16(bf16x8 a, bf16x8 b, f32x4 c) {
  return __builtin_amdgcn_mfma_f32_16x16x32_bf16(a, b, c, 0, 0, 0);
}

// ---------------- fused fp32 -> bf16 casts, grid-stride (G11) ----------------
// One dispatch for all three weight/activation casts; 2048 blocks grid-stride
// replaces 50k single-f32x4 workgroups (dispatch overhead + better ILP).
__global__ __launch_bounds__(256) void cast3_kernel(const float* __restrict__ a, bf16* __restrict__ oa, int na,
                                                    const float* __restrict__ b, bf16* __restrict__ ob, int nb,
                                                    const float* __restrict__ c, bf16* __restrict__ oc, int nc) {
  int stride = gridDim.x * 256;
  int t0 = blockIdx.x * 256 + threadIdx.x;
  for (int i = t0; i < na; i += stride) {
    f32x4 v = ((const f32x4*)a)[i];
    bf16x4 o = { (bf16)v[0], (bf16)v[1], (bf16)v[2], (bf16)v[3] };
    ((bf16x4*)oa)[i] = o;
  }
  for (int i = t0; i < nb; i += stride) {
    f32x4 v = ((const f32x4*)b)[i];
    bf16x4 o = { (bf16)v[0], (bf16)v[1], (bf16)v[2], (bf16)v[3] };
    ((bf16x4*)ob)[i] = o;
  }
  for (int i = t0; i < nc; i += stride) {
    f32x4 v = ((const f32x4*)c)[i];
    bf16x4 o = { (bf16)v[0], (bf16)v[1], (bf16)v[2], (bf16)v[3] };
    ((bf16x4*)oc)[i] = o;
  }
}

// ---------------- fp32 partial-sum reduce: out = a + b, grid-stride ----------------
__global__ __launch_bounds__(256) void add2_kernel(const float* __restrict__ a,
                                                   const float* __restrict__ b,
                                                   float* __restrict__ o, int n4) {
  int stride = gridDim.x * 256;
  for (int i = blockIdx.x * 256 + threadIdx.x; i < n4; i += stride) {
    f32x4 x = ((const f32x4*)a)[i];
    f32x4 y = ((const f32x4*)b)[i];
    ((f32x4*)o)[i] = x + y;
  }
}

// ================= shared GEMM machinery (256x256 tile, 8 waves 2Mx4N) =============
// Frozen since R5: ~950 TF QKV, MfmaUtil ~39%. R1-R5 sync permutations all land
// 31-39% -> structure plateau at this geometry (1 block/CU, 8-wave lockstep).
#define GSTG(gb, lb, kk, half, LDAB) do {                              \
    const bf16* _g = (gb) + (size_t)((half) * 128) * (LDAB) + (kk);    \
    bf16* _l = (lb) + (half) * 128 * 64 + soff;                        \
    async16(_g, _l);                                                   \
    async16(_g + (size_t)64 * (LDAB), _l + 64 * 64);                   \
  } while (0)
#define LD12(ab, bb, cx, ar, br) do {                                  \
    const bf16* _pa = (ab) + arow;                                     \
    const bf16* _pb = (bb) + brow;                                     \
    _Pragma("unroll")                                                  \
    for (int _i = 0; _i < 8; _i++) ar[_i] = *(const bf16x8*)(_pa + _i * 16 * 64 + (cx)); \
    _Pragma("unroll")                                                  \
    for (int _j = 0; _j < 4; _j++) br[_j] = *(const bf16x8*)(_pb + _j * 16 * 64 + (cx)); \
  } while (0)
#define MM32(ar, br) do {                                              \
    __builtin_amdgcn_s_setprio(1);                                     \
    _Pragma("unroll")                                                  \
    for (int _i = 0; _i < 8; _i++)                                     \
      _Pragma("unroll")                                                \
      for (int _j = 0; _j < 4; _j++)                                   \
        acc[_i][_j] = mfma16(ar[_i], br[_j], acc[_i][_j]);             \
    __builtin_amdgcn_s_setprio(0);                                     \
  } while (0)
#define BARS() do { __builtin_amdgcn_s_barrier(); __builtin_amdgcn_sched_barrier(0); } while (0)
#define LGKM0() asm volatile("s_waitcnt lgkmcnt(0)" ::: "memory")
#define WAITV8() asm volatile("s_waitcnt vmcnt(8)" ::: "memory")

#define GEMM_PIPE_BODY(LDAB)                                           \
  f32x4 acc[8][4];                                                     \
  _Pragma("unroll")                                                    \
  for (int i = 0; i < 8; i++)                                          \
    _Pragma("unroll")                                                  \
    for (int j = 0; j < 4; j++) { f32x4 z = {0.f, 0.f, 0.f, 0.f}; acc[i][j] = z; } \
  bf16x8 a0[8], b0[4], a1[8], b1[4];                                   \
  const int nT = K >> 6;                                               \
  const int nIter = K >> 7;                                            \
  GSTG(Ag, As0, 0, 0, LDAB); GSTG(Ag, As0, 0, 1, LDAB);                \
  GSTG(Bg, Bs0, 0, 0, LDAB); GSTG(Bg, Bs0, 0, 1, LDAB);                \
  GSTG(Ag, As1, 64, 0, LDAB); GSTG(Ag, As1, 64, 1, LDAB);              \
  GSTG(Bg, Bs1, 64, 0, LDAB); GSTG(Bg, Bs1, 64, 1, LDAB);              \
  WAITV8();                                                            \
  BARS();                                                              \
  LD12(As0, Bs0, c0, a0, b0);                                          \
  for (int t = 0; t < nIter; t++) {                                    \
    int t2 = 2 * t + 2; if (t2 > nT - 1) t2 = nT - 1;                  \
    int t3 = 2 * t + 3; if (t3 > nT - 1) t3 = nT - 1;                  \
    int k2 = t2 * 64, k3 = t3 * 64;                                    \
    /* Ph1: tile even (buf0) — load slice1, compute slice0 */          \
    LD12(As0, Bs0, c1, a1, b1);                                        \
    MM32(a0, b0);                                                      \
    LGKM0();                                                           \
    BARS();                                                            \
    /* Ph2: restage buf0, compute slice1 */                            \
    GSTG(Ag, As0, k2, 0, LDAB); GSTG(Ag, As0, k2, 1, LDAB);            \
    GSTG(Bg, Bs0, k2, 0, LDAB); GSTG(Bg, Bs0, k2, 1, LDAB);            \
    MM32(a1, b1);                                                      \
    WAITV8();                                                          \
    BARS();                                                            \
    LD12(As1, Bs1, c0, a0, b0);                                        \
    /* Ph3: tile odd (buf1) */                                         \
    LD12(As1, Bs1, c1, a1, b1);                                        \
    MM32(a0, b0);                                                      \
    LGKM0();                                                           \
    BARS();                                                            \
    /* Ph4 */                                                          \
    GSTG(Ag, As1, k3, 0, LDAB); GSTG(Ag, As1, k3, 1, LDAB);            \
    GSTG(Bg, Bs1, k3, 0, LDAB); GSTG(Bg, Bs1, k3, 1, LDAB);            \
    MM32(a1, b1);                                                      \
    WAITV8();                                                          \
    BARS();                                                            \
    LD12(As0, Bs0, c0, a0, b0);                                        \
  }

// ---------------- 8-wave 256x256 NT bf16 GEMM (QKV projection) ----------------
__global__ __launch_bounds__(512, 2) void gemm_nt_8p(const bf16* __restrict__ A,
                                                     const bf16* __restrict__ B,
                                                     float* __restrict__ C,
                                                     int M, int N, int K) {
  __shared__ bf16 As0[256 * 64];
  __shared__ bf16 Bs0[256 * 64];
  __shared__ bf16 As1[256 * 64];
  __shared__ bf16 Bs1[256 * 64];
  int tid = threadIdx.x;
  int lane = tid & 63;
  int w = tid >> 6;
  int wm = w >> 2, wn = w & 3;
  int lid = blockIdx.x;
  int oid = (lid & 7) * 32 + (lid >> 3);
  int rect = oid >> 5, ri = oid & 31;
  int bm = (rect & 3) * 2 + (ri >> 4);
  int bn = (rect >> 2) * 16 + (ri & 15);
  int srow = tid >> 3, schunk = tid & 7;
  int gcol = (schunk ^ (srow & 7)) * 8;
  const bf16* Ag = A + (size_t)(bm * 256 + srow) * K + gcol;
  const bf16* Bg = B + (size_t)(bn * 256 + srow) * K + gcol;
  int soff = srow * 64 + schunk * 8;
  int fr = lane & 15, fq = lane >> 4;
  int c0 = ((fq) ^ (fr & 7)) * 8;
  int c1 = ((4 + fq) ^ (fr & 7)) * 8;
  const int arow = (wm * 128 + fr) * 64;
  const int brow = (wn * 64 + fr) * 64;

  GEMM_PIPE_BODY(K)

  int row0 = bm * 256 + wm * 128 + fq * 4;
  int col0 = bn * 256 + wn * 64 + fr;
#pragma unroll
  for (int i = 0; i < 8; i++)
#pragma unroll
    for (int j = 0; j < 4; j++)
#pragma unroll
      for (int r = 0; r < 4; r++)
        C[(size_t)(row0 + i * 16 + r) * N + col0 + j * 16] = acc[i][j][r];
}

// ---------------- split-K=2 variant for the output projection ----------------
__global__ __launch_bounds__(512, 2) void gemm_nt_8p_ks(const bf16* __restrict__ A,
                                                        const bf16* __restrict__ B,
                                                        float* __restrict__ C,
                                                        int M, int N, int K, int lda) {
  __shared__ bf16 As0[256 * 64];
  __shared__ bf16 Bs0[256 * 64];
  __shared__ bf16 As1[256 * 64];
  __shared__ bf16 Bs1[256 * 64];
  int tid = threadIdx.x;
  int lane = tid & 63;
  int w = tid >> 6;
  int wm = w >> 2, wn = w & 3;
  int lid = blockIdx.x;
  int ks = lid >= 112;
  int l2 = lid - ks * 112;
  int oid = (l2 & 7) * 14 + (l2 >> 3);
  int bm = oid / 14;
  int bn = oid - bm * 14;
  int kbase = ks * K;
  float* Cp = C + (size_t)ks * M * N;
  int srow = tid >> 3, schunk = tid & 7;
  int gcol = (schunk ^ (srow & 7)) * 8;
  const bf16* Ag = A + (size_t)(bm * 256 + srow) * lda + kbase + gcol;
  const bf16* Bg = B + (size_t)(bn * 256 + srow) * lda + kbase + gcol;
  int soff = srow * 64 + schunk * 8;
  int fr = lane & 15, fq = lane >> 4;
  int c0 = ((fq) ^ (fr & 7)) * 8;
  int c1 = ((4 + fq) ^ (fr & 7)) * 8;
  const int arow = (wm * 128 + fr) * 64;
  const int brow = (wn * 64 + fr) * 64;

  GEMM_PIPE_BODY(lda)

  int row0 = bm * 256 + wm * 128 + fq * 4;
  int col0 = bn * 256 + wn * 64 + fr;
#pragma unroll
  for (int i = 0; i < 8; i++)
#pragma unroll
    for (int j = 0; j < 4; j++)
#pragma unroll
      for (int r = 0; r < 4; r++)
        Cp[(size_t)(row0 + i * 16 + r) * N + col0 + j * 16] = acc[i][j][r];
}

// ---------------- RMSNorm + RoPE + q-scale; one wave per (s, head) ----------------
__global__ __launch_bounds__(256) void qk_norm_rope(const float* __restrict__ qkv,
                                                    const float* __restrict__ cosb,
                                                    const float* __restrict__ sinb,
                                                    const float* __restrict__ qw,
                                                    const float* __restrict__ kw,
                                                    bf16* __restrict__ qout,
                                                    bf16* __restrict__ kout) {
  int s = blockIdx.x;
  int lane = threadIdx.x & 63;
  int w = threadIdx.x >> 6;
  int d0 = lane * 4;
  int dr = d0 & 127;
  f32x4 cv = *(const f32x4*)(cosb + s * 128 + dr);
  f32x4 sv = *(const f32x4*)(sinb + s * 128 + dr);
  bool hi = lane >= 32;
#pragma unroll
  for (int r = 0; r < 6; r++) {
    int head = r * 4 + w;  // 0..23 : 16 q heads then 8 k heads
    const float* x = qkv + (size_t)s * QKV_O + head * HDIM + d0;
    f32x4 v = *(const f32x4*)x;
    float ss = v[0] * v[0] + v[1] * v[1] + v[2] * v[2] + v[3] * v[3];
#pragma unroll
    for (int off = 32; off > 0; off >>= 1) ss += __shfl_xor(ss, off);
    float scale = rsqrtf(ss * (1.0f / HDIM) + 1e-6f);
    bool isq = head < NHEADS;
    const float* wn = isq ? qw : kw;
    f32x4 wv = *(const f32x4*)(wn + d0);
    float y[4], o[4];
#pragma unroll
    for (int i = 0; i < 4; i++) y[i] = v[i] * scale * (1.0f + wv[i]);
#pragma unroll
    for (int i = 0; i < 4; i++) {
      float py = __shfl_xor(y[i], 32);
      o[i] = hi ? (py * sv[i] + y[i] * cv[i]) : (y[i] * cv[i] - py * sv[i]);
    }
    float mult = isq ? 0.0625f : 1.0f;  // SCALING = 256^-0.5 folded into q
    bf16x4 ov = { (bf16)(o[0] * mult), (bf16)(o[1] * mult), (bf16)(o[2] * mult), (bf16)(o[3] * mult) };
    if (isq) *(bf16x4*)(qout + ((size_t)head * S_LEN + s) * HDIM + d0) = ov;
    else     *(bf16x4*)(kout + ((size_t)(head - NHEADS) * S_LEN + s) * HDIM + d0) = ov;
  }
}

// ---------------- V transpose: qkv fp32 [s][6144+h*256+d] -> vt bf16 [h][d][s] ----------------
__global__ __launch_bounds__(256) void v_transpose(const float* __restrict__ qkv, bf16* __restrict__ vt) {
  __shared__ float tile[64][65];
  int dt = blockIdx.x, st = blockIdx.y, h = blockIdx.z;
  int t = threadIdx.x;
  int d0 = dt * 64, s0 = st * 64;
#pragma unroll
  for (int i = 0; i < 16; i++) {
    int idx = i * 256 + t;
    int r = idx >> 6, c = idx & 63;
    tile[r][c] = qkv[(size_t)(s0 + r) * QKV_O + 6144 + h * HDIM + d0 + c];
  }
  __syncthreads();
#pragma unroll
  for (int i = 0; i < 16; i++) {
    int idx = i * 256 + t;
    int dr = idx >> 6, sc = idx & 63;
    vt[((size_t)h * HDIM + d0 + dr) * S_LEN + s0 + sc] = (bf16)tile[sc][dr];
  }
}

// ---------------- Flash attention: 128 q-rows/block, 32 rows/WAVE, Bk=32 ----------------
// R7: LDS-traffic halving. The per-wave K/V-tile re-read (16+16 ds_read_b128 per
// wave-iter) is the dominant LDS-throughput term; it is invariant in rows/wave, so
// 32 rows/wave (two 16-row MFMA tiles A/B) makes every b0/b1 and vf read feed TWO
// MFMAs -> LDS bytes per score halved. Grid 16x16 = 256 blocks = 1/CU (4 waves/CU;
// VGPR ~250 fine at 1 wave/SIMD, budget 512). Staging/swizzles/ping-pong identical
// to R6 (vmcnt(8) counted; conflict-free patterns re-verified by bank arithmetic).
#define PSTRIDE 40
__global__ __launch_bounds__(256) void attn_kernel(const bf16* __restrict__ q,
                                                   const bf16* __restrict__ kx,
                                                   const bf16* __restrict__ vt,
                                                   bf16* __restrict__ aout) {
  __shared__ bf16 kt[2][32 * 256];          // K-tile [k'][d], row-rotation swizzle
  __shared__ bf16 vtile[2][256 * 32];       // V-tile [d][k'], XOR chunk swizzle
  __shared__ bf16 pbuf[4][2][16 * PSTRIDE]; // per-wave, per-rowtile P staging
  int h = blockIdx.x;
  int qt = blockIdx.y;             // 16 q-tiles of 128 rows
  int kvh = h >> 1;                // GQA
  int tid = threadIdx.x;
  int lane = tid & 63, w = tid >> 6;
  int fr = lane & 15, fq = lane >> 4;
  int qs = qt * 128;
  // Q fragments for both row-tiles (rows qs + w*32 + [0,16) and + [16,32))
  bf16x8 qfA[8], qfB[8];
  const bf16* qbA = q + ((size_t)h * S_LEN + qs + w * 32 + fr) * HDIM + fq * 8;
  const bf16* qbB = qbA + (size_t)16 * HDIM;
#pragma unroll
  for (int i = 0; i < 8; i++) { qfA[i] = *(const bf16x8*)(qbA + i * 32); qfB[i] = *(const bf16x8*)(qbB + i * 32); }
  f32x4 accA[16], accB[16];
#pragma unroll
  for (int i = 0; i < 16; i++) { f32x4 z = {0.f, 0.f, 0.f, 0.f}; accA[i] = z; accB[i] = z; }
  float lsumA[4] = {0.f, 0.f, 0.f, 0.f};
  float lsumB[4] = {0.f, 0.f, 0.f, 0.f};
  // staging lane roles (8 async16 per thread per tile: 4 K + 4 V) — as R6
  int krow = w * 2 + (lane >> 5);
  int kcolr = (lane & 31) * 8;
  const bf16* kg = kx + (size_t)kvh * S_LEN * HDIM;
  int vd = w * 16 + (lane >> 2);
  int vsw = (vd >> 1) & 3;
  int vcl = (lane & 3) * 8;
  int vcg = (((lane & 3) ^ vsw) * 8);
  const bf16* vg = vt + (size_t)kvh * HDIM * S_LEN;
  int rot0 = (fq * 8 - fr * 8) & 255;
  int rot1 = (fq * 8 - fr * 8 - 128) & 255;
  int fsw = (fr >> 1) & 3;
  int kmax = qs + 128;

#define ASTG(KK, B) do {                                                   \
    bf16* _kb = &kt[(B)][0]; bf16* _vb = &vtile[(B)][0];                   \
    _Pragma("unroll")                                                      \
    for (int p = 0; p < 4; p++) {                                          \
      int r = p * 8 + krow;                                                \
      int gc = (kcolr + r * 8) & 255;                                      \
      async16(kg + (size_t)((KK) + r) * HDIM + gc, _kb + r * 256 + kcolr); \
      int d = p * 64 + vd;                                                 \
      async16(vg + (size_t)d * S_LEN + (KK) + vcg, _vb + d * 32 + vcl);    \
    }                                                                      \
  } while (0)

  ASTG(0, 0);
  int ib = 0;
  for (int k0 = 0; k0 < kmax; k0 += 32, ib ^= 1) {
    __builtin_amdgcn_s_barrier();            // all waves done reading buf ib^1
    __builtin_amdgcn_sched_barrier(0);
    if (k0 + 32 < kmax) {
      ASTG(k0 + 32, ib ^ 1);                 // next tile issue; latency hides under compute
      asm volatile("s_waitcnt vmcnt(8)" ::: "memory");  // current tile's 8 loads done
    } else {
      asm volatile("s_waitcnt vmcnt(0)" ::: "memory");
    }
    __builtin_amdgcn_sched_barrier(0);
    __builtin_amdgcn_s_barrier();            // everyone's current loads landed
    __builtin_amdgcn_sched_barrier(0);
    const bf16* ktb = &kt[ib][0];
    const bf16* vtb = &vtile[ib][0];
    const bf16* kt0 = ktb + fr * 256;
    const bf16* kt1 = ktb + (16 + fr) * 256;
    // QK^T: each K-fragment read feeds both row-tiles (2 MFMAs per read)
    f32x4 s0a = {0.f, 0.f, 0.f, 0.f}, s1a = {0.f, 0.f, 0.f, 0.f};
    f32x4 s0b = {0.f, 0.f, 0.f, 0.f}, s1b = {0.f, 0.f, 0.f, 0.f};
    __builtin_amdgcn_s_setprio(1);
#pragma unroll
    for (int kk = 0; kk < 8; kk++) {
      bf16x8 b0 = *(const bf16x8*)(kt0 + ((kk * 32 + rot0) & 255));
      bf16x8 b1 = *(const bf16x8*)(kt1 + ((kk * 32 + rot1) & 255));
      s0a = mfma16(qfA[kk], b0, s0a);
      s1a = mfma16(qfA[kk], b1, s1a);
      s0b = mfma16(qfB[kk], b0, s0b);
      s1b = mfma16(qfB[kk], b1, s1b);
    }
    __builtin_amdgcn_s_setprio(0);
    // softcap + causal mask + fixed-max exp, both row-tiles
#pragma unroll
    for (int reg = 0; reg < 4; reg++) {
      int rowgA = qs + w * 32 + fq * 4 + reg;
      int rowgB = rowgA + 16;
      float u0 = __builtin_amdgcn_exp2f(0.057707802f * s0a[reg]);
      float u1 = __builtin_amdgcn_exp2f(0.057707802f * s1a[reg]);
      float p0 = __builtin_amdgcn_exp2f(28.853901f - 144.26950f * __builtin_amdgcn_rcpf(u0 + 1.0f));
      float p1 = __builtin_amdgcn_exp2f(28.853901f - 144.26950f * __builtin_amdgcn_rcpf(u1 + 1.0f));
      p0 = (k0 + fr <= rowgA) ? p0 : 0.0f;
      p1 = (k0 + 16 + fr <= rowgA) ? p1 : 0.0f;
      lsumA[reg] += p0 + p1;
      pbuf[w][0][(fq * 4 + reg) * PSTRIDE + fr] = (bf16)p0;
      pbuf[w][0][(fq * 4 + reg) * PSTRIDE + 16 + fr] = (bf16)p1;
      float v0 = __builtin_amdgcn_exp2f(0.057707802f * s0b[reg]);
      float v1 = __builtin_amdgcn_exp2f(0.057707802f * s1b[reg]);
      float q0 = __builtin_amdgcn_exp2f(28.853901f - 144.26950f * __builtin_amdgcn_rcpf(v0 + 1.0f));
      float q1 = __builtin_amdgcn_exp2f(28.853901f - 144.26950f * __builtin_amdgcn_rcpf(v1 + 1.0f));
      q0 = (k0 + fr <= rowgB) ? q0 : 0.0f;
      q1 = (k0 + 16 + fr <= rowgB) ? q1 : 0.0f;
      lsumB[reg] += q0 + q1;
      pbuf[w][1][(fq * 4 + reg) * PSTRIDE + fr] = (bf16)q0;
      pbuf[w][1][(fq * 4 + reg) * PSTRIDE + 16 + fr] = (bf16)q1;
    }
    // PV: each V-fragment read feeds both row-tiles
    bf16x8 pfA = *(const bf16x8*)&pbuf[w][0][fr * PSTRIDE + fq * 8];
    bf16x8 pfB = *(const bf16x8*)&pbuf[w][1][fr * PSTRIDE + fq * 8];
    __builtin_amdgcn_s_setprio(1);
#pragma unroll
    for (int ct = 0; ct < 16; ct++) {
      bf16x8 vf = *(const bf16x8*)&vtb[(ct * 16 + fr) * 32 + (fq ^ fsw) * 8];
      accA[ct] = mfma16(pfA, vf, accA[ct]);
      accB[ct] = mfma16(pfB, vf, accB[ct]);
    }
    __builtin_amdgcn_s_setprio(0);
  }
#undef ASTG
  // final l reduction over the 16 fr lanes of each row, then divide
  float rlA[4], rlB[4];
#pragma unroll
  for (int reg = 0; reg < 4; reg++) {
    float la = lsumA[reg];
    la += __shfl_xor(la, 1);
    la += __shfl_xor(la, 2);
    la += __shfl_xor(la, 4);
    la += __shfl_xor(la, 8);
    rlA[reg] = 1.0f / la;
    float lb = lsumB[reg];
    lb += __shfl_xor(lb, 1);
    lb += __shfl_xor(lb, 2);
    lb += __shfl_xor(lb, 4);
    lb += __shfl_xor(lb, 8);
    rlB[reg] = 1.0f / lb;
  }
#pragma unroll
  for (int ct = 0; ct < 16; ct++)
#pragma unroll
    for (int reg = 0; reg < 4; reg++) {
      int rowA = qs + w * 32 + fq * 4 + reg;
      aout[(size_t)rowA * O_IN + h * HDIM + ct * 16 + fr] = (bf16)(accA[ct][reg] * rlA[reg]);
      aout[(size_t)(rowA + 16) * O_IN + h * HDIM + ct * 16 + fr] = (bf16)(accB[ct][reg] * rlB[reg]);
    }
}

extern "C" void kernel_launch(void* const* d_in, const int* in_sizes, int n_in,
                              void* d_out, int out_size, void* d_ws, size_t ws_size,
                              hipStream_t stream) {
  const float* hidden = (const float*)d_in[0];
  const float* cosb   = (const float*)d_in[1];
  const float* sinb   = (const float*)d_in[2];
  const float* wqkv   = (const float*)d_in[7];
  const float* wo     = (const float*)d_in[8];
  const float* qnw    = (const float*)d_in[9];
  const float* knw    = (const float*)d_in[10];
  float* out = (float*)d_out;
  char* ws = (char*)d_ws;
  bf16*  h_bf    = (bf16*)(ws + 0);          // 2048*3584*2   = 14,680,064
  bf16*  wqkv_bf = (bf16*)(ws + 14680064);   // 8192*3584*2   = 58,720,256
  bf16*  wo_bf   = (bf16*)(ws + 73400320);   // 3584*4096*2   = 29,360,128
  float* qkv     = (float*)(ws + 102760448); // 2048*8192*4   = 67,108,864
  bf16*  qb      = (bf16*)(ws + 169869312);  // 16*2048*256*2 = 16,777,216
  bf16*  kb      = (bf16*)(ws + 186646528);  // 8*2048*256*2  =  8,388,608
  bf16*  vtb     = (bf16*)(ws + 195035136);  // 8*256*2048*2  =  8,388,608
  bf16*  attnb   = (bf16*)(ws + 203423744);  // 2048*4096*2   = 16,777,216
  // split-K partials reuse the qkv region (dead after qk_norm_rope + v_transpose)
  float* part0   = (float*)(ws + 102760448);
  float* part1   = part0 + (size_t)2048 * 3584;

  cast3_kernel<<<2048, 256, 0, stream>>>(hidden, h_bf, 1835008,
                                         wqkv, wqkv_bf, 7340032,
                                         wo, wo_bf, 3670016);
  gemm_nt_8p<<<256, 512, 0, stream>>>(h_bf, wqkv_bf, qkv, 2048, 8192, 3584);
  qk_norm_rope<<<2048, 256, 0, stream>>>(qkv, cosb, sinb, qnw, knw, qb, kb);
  v_transpose<<<dim3(4, 32, 8), 256, 0, stream>>>(qkv, vtb);
  attn_kernel<<<dim3(16, 16), 256, 0, stream>>>(qb, kb, vtb, attnb);
  gemm_nt_8p_ks<<<224, 512, 0, stream>>>(attnb, wo_bf, part0, 2048, 3584, 2048, 4096);
  add2_kernel<<<2048, 256, 0, stream>>>(part0, part1, out, 1835008);
}

// Round 8
// 574.001 us; speedup vs baseline: 1.0989x; 1.0989x over previous
//
#include <hip/hip_runtime.h>

typedef __bf16 bf16;
typedef __bf16 bf16x4 __attribute__((ext_vector_type(4)));
typedef __bf16 bf16x8 __attribute__((ext_vector_type(8)));
typedef float f32x4 __attribute__((ext_vector_type(4)));

#define S_LEN 2048
#define HID   3584
#define NHEADS 16
#define NKVH   8
#define HDIM   256
#define QKV_O  8192   // (16 + 2*8) * 256
#define O_IN   4096   // 16 * 256

typedef const __attribute__((address_space(1))) void* gp_t;
typedef __attribute__((address_space(3))) void* sp_t;

__device__ __forceinline__ void async16(const void* g, void* s) {
  __builtin_amdgcn_global_load_lds((gp_t)g, (sp_t)s, 16, 0, 0);
}

__device__ __forceinline__ f32x4 mfma16(bf16x8 a, bf16x8 b, f32x4 c) {
  return __builtin_amdgcn_mfma_f32_16x16x32_bf16(a, b, c, 0, 0, 0);
}

// ---------------- fused fp32 -> bf16 casts, grid-stride ----------------
__global__ __launch_bounds__(256) void cast3_kernel(const float* __restrict__ a, bf16* __restrict__ oa, int na,
                                                    const float* __restrict__ b, bf16* __restrict__ ob, int nb,
                                                    const float* __restrict__ c, bf16* __restrict__ oc, int nc) {
  int stride = gridDim.x * 256;
  int t0 = blockIdx.x * 256 + threadIdx.x;
  for (int i = t0; i < na; i += stride) {
    f32x4 v = ((const f32x4*)a)[i];
    bf16x4 o = { (bf16)v[0], (bf16)v[1], (bf16)v[2], (bf16)v[3] };
    ((bf16x4*)oa)[i] = o;
  }
  for (int i = t0; i < nb; i += stride) {
    f32x4 v = ((const f32x4*)b)[i];
    bf16x4 o = { (bf16)v[0], (bf16)v[1], (bf16)v[2], (bf16)v[3] };
    ((bf16x4*)ob)[i] = o;
  }
  for (int i = t0; i < nc; i += stride) {
    f32x4 v = ((const f32x4*)c)[i];
    bf16x4 o = { (bf16)v[0], (bf16)v[1], (bf16)v[2], (bf16)v[3] };
    ((bf16x4*)oc)[i] = o;
  }
}

// ---------------- fp32 partial-sum reduce: out = a + b, grid-stride ----------------
__global__ __launch_bounds__(256) void add2_kernel(const float* __restrict__ a,
                                                   const float* __restrict__ b,
                                                   float* __restrict__ o, int n4) {
  int stride = gridDim.x * 256;
  for (int i = blockIdx.x * 256 + threadIdx.x; i < n4; i += stride) {
    f32x4 x = ((const f32x4*)a)[i];
    f32x4 y = ((const f32x4*)b)[i];
    ((f32x4*)o)[i] = x + y;
  }
}

// ================= shared GEMM machinery (256x256 tile, 8 waves 2Mx4N) =============
// Frozen since R5: ~950 TF QKV, MfmaUtil ~39% (structure plateau at this geometry).
#define GSTG(gb, lb, kk, half, LDAB) do {                              \
    const bf16* _g = (gb) + (size_t)((half) * 128) * (LDAB) + (kk);    \
    bf16* _l = (lb) + (half) * 128 * 64 + soff;                        \
    async16(_g, _l);                                                   \
    async16(_g + (size_t)64 * (LDAB), _l + 64 * 64);                   \
  } while (0)
#define LD12(ab, bb, cx, ar, br) do {                                  \
    const bf16* _pa = (ab) + arow;                                     \
    const bf16* _pb = (bb) + brow;                                     \
    _Pragma("unroll")                                                  \
    for (int _i = 0; _i < 8; _i++) ar[_i] = *(const bf16x8*)(_pa + _i * 16 * 64 + (cx)); \
    _Pragma("unroll")                                                  \
    for (int _j = 0; _j < 4; _j++) br[_j] = *(const bf16x8*)(_pb + _j * 16 * 64 + (cx)); \
  } while (0)
#define MM32(ar, br) do {                                              \
    __builtin_amdgcn_s_setprio(1);                                     \
    _Pragma("unroll")                                                  \
    for (int _i = 0; _i < 8; _i++)                                     \
      _Pragma("unroll")                                                \
      for (int _j = 0; _j < 4; _j++)                                   \
        acc[_i][_j] = mfma16(ar[_i], br[_j], acc[_i][_j]);             \
    __builtin_amdgcn_s_setprio(0);                                     \
  } while (0)
#define BARS() do { __builtin_amdgcn_s_barrier(); __builtin_amdgcn_sched_barrier(0); } while (0)
#define LGKM0() asm volatile("s_waitcnt lgkmcnt(0)" ::: "memory")
#define WAITV8() asm volatile("s_waitcnt vmcnt(8)" ::: "memory")

#define GEMM_PIPE_BODY(LDAB)                                           \
  f32x4 acc[8][4];                                                     \
  _Pragma("unroll")                                                    \
  for (int i = 0; i < 8; i++)                                          \
    _Pragma("unroll")                                                  \
    for (int j = 0; j < 4; j++) { f32x4 z = {0.f, 0.f, 0.f, 0.f}; acc[i][j] = z; } \
  bf16x8 a0[8], b0[4], a1[8], b1[4];                                   \
  const int nT = K >> 6;                                               \
  const int nIter = K >> 7;                                            \
  GSTG(Ag, As0, 0, 0, LDAB); GSTG(Ag, As0, 0, 1, LDAB);                \
  GSTG(Bg, Bs0, 0, 0, LDAB); GSTG(Bg, Bs0, 0, 1, LDAB);                \
  GSTG(Ag, As1, 64, 0, LDAB); GSTG(Ag, As1, 64, 1, LDAB);              \
  GSTG(Bg, Bs1, 64, 0, LDAB); GSTG(Bg, Bs1, 64, 1, LDAB);              \
  WAITV8();                                                            \
  BARS();                                                              \
  LD12(As0, Bs0, c0, a0, b0);                                          \
  for (int t = 0; t < nIter; t++) {                                    \
    int t2 = 2 * t + 2; if (t2 > nT - 1) t2 = nT - 1;                  \
    int t3 = 2 * t + 3; if (t3 > nT - 1) t3 = nT - 1;                  \
    int k2 = t2 * 64, k3 = t3 * 64;                                    \
    LD12(As0, Bs0, c1, a1, b1);                                        \
    MM32(a0, b0);                                                      \
    LGKM0();                                                           \
    BARS();                                                            \
    GSTG(Ag, As0, k2, 0, LDAB); GSTG(Ag, As0, k2, 1, LDAB);            \
    GSTG(Bg, Bs0, k2, 0, LDAB); GSTG(Bg, Bs0, k2, 1, LDAB);            \
    MM32(a1, b1);                                                      \
    WAITV8();                                                          \
    BARS();                                                            \
    LD12(As1, Bs1, c0, a0, b0);                                        \
    LD12(As1, Bs1, c1, a1, b1);                                        \
    MM32(a0, b0);                                                      \
    LGKM0();                                                           \
    BARS();                                                            \
    GSTG(Ag, As1, k3, 0, LDAB); GSTG(Ag, As1, k3, 1, LDAB);            \
    GSTG(Bg, Bs1, k3, 0, LDAB); GSTG(Bg, Bs1, k3, 1, LDAB);            \
    MM32(a1, b1);                                                      \
    WAITV8();                                                          \
    BARS();                                                            \
    LD12(As0, Bs0, c0, a0, b0);                                        \
  }

// ---------------- 8-wave 256x256 NT bf16 GEMM (QKV projection) ----------------
__global__ __launch_bounds__(512, 2) void gemm_nt_8p(const bf16* __restrict__ A,
                                                     const bf16* __restrict__ B,
                                                     float* __restrict__ C,
                                                     int M, int N, int K) {
  __shared__ bf16 As0[256 * 64];
  __shared__ bf16 Bs0[256 * 64];
  __shared__ bf16 As1[256 * 64];
  __shared__ bf16 Bs1[256 * 64];
  int tid = threadIdx.x;
  int lane = tid & 63;
  int w = tid >> 6;
  int wm = w >> 2, wn = w & 3;
  int lid = blockIdx.x;
  int oid = (lid & 7) * 32 + (lid >> 3);
  int rect = oid >> 5, ri = oid & 31;
  int bm = (rect & 3) * 2 + (ri >> 4);
  int bn = (rect >> 2) * 16 + (ri & 15);
  int srow = tid >> 3, schunk = tid & 7;
  int gcol = (schunk ^ (srow & 7)) * 8;
  const bf16* Ag = A + (size_t)(bm * 256 + srow) * K + gcol;
  const bf16* Bg = B + (size_t)(bn * 256 + srow) * K + gcol;
  int soff = srow * 64 + schunk * 8;
  int fr = lane & 15, fq = lane >> 4;
  int c0 = ((fq) ^ (fr & 7)) * 8;
  int c1 = ((4 + fq) ^ (fr & 7)) * 8;
  const int arow = (wm * 128 + fr) * 64;
  const int brow = (wn * 64 + fr) * 64;

  GEMM_PIPE_BODY(K)

  int row0 = bm * 256 + wm * 128 + fq * 4;
  int col0 = bn * 256 + wn * 64 + fr;
#pragma unroll
  for (int i = 0; i < 8; i++)
#pragma unroll
    for (int j = 0; j < 4; j++)
#pragma unroll
      for (int r = 0; r < 4; r++)
        C[(size_t)(row0 + i * 16 + r) * N + col0 + j * 16] = acc[i][j][r];
}

// ---------------- split-K=2 variant for the output projection ----------------
__global__ __launch_bounds__(512, 2) void gemm_nt_8p_ks(const bf16* __restrict__ A,
                                                        const bf16* __restrict__ B,
                                                        float* __restrict__ C,
                                                        int M, int N, int K, int lda) {
  __shared__ bf16 As0[256 * 64];
  __shared__ bf16 Bs0[256 * 64];
  __shared__ bf16 As1[256 * 64];
  __shared__ bf16 Bs1[256 * 64];
  int tid = threadIdx.x;
  int lane = tid & 63;
  int w = tid >> 6;
  int wm = w >> 2, wn = w & 3;
  int lid = blockIdx.x;
  int ks = lid >= 112;
  int l2 = lid - ks * 112;
  int oid = (l2 & 7) * 14 + (l2 >> 3);
  int bm = oid / 14;
  int bn = oid - bm * 14;
  int kbase = ks * K;
  float* Cp = C + (size_t)ks * M * N;
  int srow = tid >> 3, schunk = tid & 7;
  int gcol = (schunk ^ (srow & 7)) * 8;
  const bf16* Ag = A + (size_t)(bm * 256 + srow) * lda + kbase + gcol;
  const bf16* Bg = B + (size_t)(bn * 256 + srow) * lda + kbase + gcol;
  int soff = srow * 64 + schunk * 8;
  int fr = lane & 15, fq = lane >> 4;
  int c0 = ((fq) ^ (fr & 7)) * 8;
  int c1 = ((4 + fq) ^ (fr & 7)) * 8;
  const int arow = (wm * 128 + fr) * 64;
  const int brow = (wn * 64 + fr) * 64;

  GEMM_PIPE_BODY(lda)

  int row0 = bm * 256 + wm * 128 + fq * 4;
  int col0 = bn * 256 + wn * 64 + fr;
#pragma unroll
  for (int i = 0; i < 8; i++)
#pragma unroll
    for (int j = 0; j < 4; j++)
#pragma unroll
      for (int r = 0; r < 4; r++)
        Cp[(size_t)(row0 + i * 16 + r) * N + col0 + j * 16] = acc[i][j][r];
}

// ---------------- RMSNorm + RoPE + q-scale; one wave per (s, head) ----------------
__global__ __launch_bounds__(256) void qk_norm_rope(const float* __restrict__ qkv,
                                                    const float* __restrict__ cosb,
                                                    const float* __restrict__ sinb,
                                                    const float* __restrict__ qw,
                                                    const float* __restrict__ kw,
                                                    bf16* __restrict__ qout,
                                                    bf16* __restrict__ kout) {
  int s = blockIdx.x;
  int lane = threadIdx.x & 63;
  int w = threadIdx.x >> 6;
  int d0 = lane * 4;
  int dr = d0 & 127;
  f32x4 cv = *(const f32x4*)(cosb + s * 128 + dr);
  f32x4 sv = *(const f32x4*)(sinb + s * 128 + dr);
  bool hi = lane >= 32;
#pragma unroll
  for (int r = 0; r < 6; r++) {
    int head = r * 4 + w;  // 0..23 : 16 q heads then 8 k heads
    const float* x = qkv + (size_t)s * QKV_O + head * HDIM + d0;
    f32x4 v = *(const f32x4*)x;
    float ss = v[0] * v[0] + v[1] * v[1] + v[2] * v[2] + v[3] * v[3];
#pragma unroll
    for (int off = 32; off > 0; off >>= 1) ss += __shfl_xor(ss, off);
    float scale = rsqrtf(ss * (1.0f / HDIM) + 1e-6f);
    bool isq = head < NHEADS;
    const float* wn = isq ? qw : kw;
    f32x4 wv = *(const f32x4*)(wn + d0);
    float y[4], o[4];
#pragma unroll
    for (int i = 0; i < 4; i++) y[i] = v[i] * scale * (1.0f + wv[i]);
#pragma unroll
    for (int i = 0; i < 4; i++) {
      float py = __shfl_xor(y[i], 32);
      o[i] = hi ? (py * sv[i] + y[i] * cv[i]) : (y[i] * cv[i] - py * sv[i]);
    }
    float mult = isq ? 0.0625f : 1.0f;  // SCALING = 256^-0.5 folded into q
    bf16x4 ov = { (bf16)(o[0] * mult), (bf16)(o[1] * mult), (bf16)(o[2] * mult), (bf16)(o[3] * mult) };
    if (isq) *(bf16x4*)(qout + ((size_t)head * S_LEN + s) * HDIM + d0) = ov;
    else     *(bf16x4*)(kout + ((size_t)(head - NHEADS) * S_LEN + s) * HDIM + d0) = ov;
  }
}

// ---------------- V transpose: qkv fp32 [s][6144+h*256+d] -> vt bf16 [h][d][s] ----------------
__global__ __launch_bounds__(256) void v_transpose(const float* __restrict__ qkv, bf16* __restrict__ vt) {
  __shared__ float tile[64][65];
  int dt = blockIdx.x, st = blockIdx.y, h = blockIdx.z;
  int t = threadIdx.x;
  int d0 = dt * 64, s0 = st * 64;
#pragma unroll
  for (int i = 0; i < 16; i++) {
    int idx = i * 256 + t;
    int r = idx >> 6, c = idx & 63;
    tile[r][c] = qkv[(size_t)(s0 + r) * QKV_O + 6144 + h * HDIM + d0 + c];
  }
  __syncthreads();
#pragma unroll
  for (int i = 0; i < 16; i++) {
    int idx = i * 256 + t;
    int dr = idx >> 6, sc = idx & 63;
    vt[((size_t)h * HDIM + d0 + dr) * S_LEN + s0 + sc] = (bf16)tile[sc][dr];
  }
}

// ---------------- Flash attention v3: 64 q-rows/block, 8 waves, column-split ----------------
// R8: attn was latency-serialized (R7 counters: MfmaUtil 9.8, VALUBusy 15, Occ 6.4%)
// and load-imbalanced (1 block/CU, work ~ qt+1). Fix: restore R6's balanced qt-pairing
// grid (16x32, 2 blocks/CU) AND split score COLUMNS across two wave-groups:
//   waves 0-3 (A): k' 0..15  (reads kt half 0 only, 8 QK MFMAs)
//   waves 4-7 (B): k' 16..31 (kt half 1)
// P exchanged via pbuf (lgkmcnt(0)+barrier), PV splits by OUTPUT columns (A: d 0..127,
// B: d 128..255) so acc never merges; only lsum merges once at the end via lred.
// Per-wave per-iter: 8 kt + 8 vf + 1 pf ds_reads (was 33), 16 MFMAs (was 32),
// acc 32 f32 (was 64) -> VGPR ~100, launch_bounds(512,4) -> 16 waves/CU = 4/SIMD.
#define PSTRIDE 40
__global__ __launch_bounds__(512, 4) void attn_kernel(const bf16* __restrict__ q,
                                                      const bf16* __restrict__ kx,
                                                      const bf16* __restrict__ vt,
                                                      bf16* __restrict__ aout) {
  __shared__ bf16 kt[2][32 * 256];       // K-tile [k'][d], row-rotation swizzle
  __shared__ bf16 vtile[2][256 * 32];    // V-tile [d][k'], XOR chunk swizzle
  __shared__ bf16 pbuf[4][16 * PSTRIDE]; // per-row-group P staging (32 cols/row)
  __shared__ float lred[8][16];          // per-wave reduced lsum for cross-group merge
  int h = blockIdx.x;
  int y = blockIdx.y;
  int qt = (y < 16) ? y : 47 - y;  // balance pairing: CU's 2 blocks sum to 31 -> const work
  int kvh = h >> 1;                // GQA
  int tid = threadIdx.x;
  int lane = tid & 63, w = tid >> 6;   // w 0..7
  int wr = w & 3;                       // row-group (rows wr*16..wr*16+15)
  int gB = w >> 2;                      // 0 = cols 0..15, 1 = cols 16..31
  int fr = lane & 15, fq = lane >> 4;
  int qs = qt * 64;
  bf16x8 qf[8];
  const bf16* qb = q + ((size_t)h * S_LEN + qs + wr * 16 + fr) * HDIM + fq * 8;
#pragma unroll
  for (int i = 0; i < 8; i++) qf[i] = *(const bf16x8*)(qb + i * 32);
  f32x4 acc[8];
#pragma unroll
  for (int i = 0; i < 8; i++) { f32x4 z = {0.f, 0.f, 0.f, 0.f}; acc[i] = z; }
  float lsum[4] = {0.f, 0.f, 0.f, 0.f};
  // staging roles: 4 async16/thread (2 K + 2 V), 512 threads cover 16KB+16KB
  int krow = w * 2 + (lane >> 5);        // 0..15
  int kcolr = (lane & 31) * 8;
  const bf16* kg = kx + (size_t)kvh * S_LEN * HDIM;
  int vd = w * 16 + (lane >> 2);         // 0..127
  int vsw = (vd >> 1) & 3;
  int vcl = (lane & 3) * 8;
  int vcg = (((lane & 3) ^ vsw) * 8);
  const bf16* vg = vt + (size_t)kvh * HDIM * S_LEN;
  // fragment roles: group A reads kt rows fr (rot0), group B rows 16+fr (rot1)
  int rot = gB ? ((fq * 8 - fr * 8 - 128) & 255) : ((fq * 8 - fr * 8) & 255);
  int ktrow = gB * 16 + fr;
  int fsw = (fr >> 1) & 3;
  int kmax = qs + 64;

#define ASTG(KK, B) do {                                                   \
    bf16* _kb = &kt[(B)][0]; bf16* _vb = &vtile[(B)][0];                   \
    _Pragma("unroll")                                                      \
    for (int p = 0; p < 2; p++) {                                          \
      int r = p * 16 + krow;                                               \
      int gc = (kcolr + r * 8) & 255;                                      \
      async16(kg + (size_t)((KK) + r) * HDIM + gc, _kb + r * 256 + kcolr); \
      int d = p * 128 + vd;                                                \
      async16(vg + (size_t)d * S_LEN + (KK) + vcg, _vb + d * 32 + vcl);    \
    }                                                                      \
  } while (0)

  ASTG(0, 0);
  int ib = 0;
  for (int k0 = 0; k0 < kmax; k0 += 32, ib ^= 1) {
    __builtin_amdgcn_s_barrier();            // all waves done reading buf ib^1 (WAR)
    __builtin_amdgcn_sched_barrier(0);
    if (k0 + 32 < kmax) {
      ASTG(k0 + 32, ib ^ 1);                 // issue next tile; latency hides under compute
      asm volatile("s_waitcnt vmcnt(4)" ::: "memory");  // current tile's 4 loads done
    } else {
      asm volatile("s_waitcnt vmcnt(0)" ::: "memory");
    }
    __builtin_amdgcn_sched_barrier(0);
    __builtin_amdgcn_s_barrier();            // everyone's current loads landed
    __builtin_amdgcn_sched_barrier(0);
    const bf16* ktb = &kt[ib][0];
    const bf16* vtb = &vtile[ib][0];
    const bf16* ktg = ktb + ktrow * 256;
    // QK^T: this group's 16 score columns only
    f32x4 s = {0.f, 0.f, 0.f, 0.f};
    __builtin_amdgcn_s_setprio(1);
#pragma unroll
    for (int kk = 0; kk < 8; kk++) {
      bf16x8 b0 = *(const bf16x8*)(ktg + ((kk * 32 + rot) & 255));
      s = mfma16(qf[kk], b0, s);
    }
    __builtin_amdgcn_s_setprio(0);
    // softcap + causal mask + fixed-max exp on 16 cols (col = k0 + gB*16 + fr)
    int cbase = k0 + gB * 16;
#pragma unroll
    for (int reg = 0; reg < 4; reg++) {
      int rowg = qs + wr * 16 + fq * 4 + reg;
      float u = __builtin_amdgcn_exp2f(0.057707802f * s[reg]);
      float p = __builtin_amdgcn_exp2f(28.853901f - 144.26950f * __builtin_amdgcn_rcpf(u + 1.0f));
      p = (cbase + fr <= rowg) ? p : 0.0f;
      lsum[reg] += p;
      pbuf[wr][(fq * 4 + reg) * PSTRIDE + gB * 16 + fr] = (bf16)p;
    }
    // publish P halves to the partner group
    asm volatile("s_waitcnt lgkmcnt(0)" ::: "memory");
    __builtin_amdgcn_s_barrier();
    __builtin_amdgcn_sched_barrier(0);
    // PV: full P row (both halves), this group's 8 output d-tiles
    bf16x8 pf = *(const bf16x8*)&pbuf[wr][fr * PSTRIDE + fq * 8];
    __builtin_amdgcn_s_setprio(1);
#pragma unroll
    for (int ct = 0; ct < 8; ct++) {
      int cte = gB * 8 + ct;
      bf16x8 vf = *(const bf16x8*)&vtb[(cte * 16 + fr) * 32 + (fq ^ fsw) * 8];
      acc[ct] = mfma16(pf, vf, acc[ct]);
    }
    __builtin_amdgcn_s_setprio(0);
  }
#undef ASTG
  // lsum: reduce over fr lanes, then merge the two column groups via lred
  float lown[4];
#pragma unroll
  for (int reg = 0; reg < 4; reg++) {
    float l = lsum[reg];
    l += __shfl_xor(l, 1);
    l += __shfl_xor(l, 2);
    l += __shfl_xor(l, 4);
    l += __shfl_xor(l, 8);
    lown[reg] = l;
    if (fr == 0) lred[w][fq * 4 + reg] = l;
  }
  asm volatile("s_waitcnt lgkmcnt(0)" ::: "memory");
  __builtin_amdgcn_s_barrier();
  __builtin_amdgcn_sched_barrier(0);
  float rl[4];
#pragma unroll
  for (int reg = 0; reg < 4; reg++)
    rl[reg] = 1.0f / (lown[reg] + lred[w ^ 4][fq * 4 + reg]);
#pragma unroll
  for (int ct = 0; ct < 8; ct++) {
    int cte = gB * 8 + ct;
#pragma unroll
    for (int reg = 0; reg < 4; reg++)
      aout[(size_t)(qs + wr * 16 + fq * 4 + reg) * O_IN + h * HDIM + cte * 16 + fr] =
          (bf16)(acc[ct][reg] * rl[reg]);
  }
}

extern "C" void kernel_launch(void* const* d_in, const int* in_sizes, int n_in,
                              void* d_out, int out_size, void* d_ws, size_t ws_size,
                              hipStream_t stream) {
  const float* hidden = (const float*)d_in[0];
  const float* cosb   = (const float*)d_in[1];
  const float* sinb   = (const float*)d_in[2];
  const float* wqkv   = (const float*)d_in[7];
  const float* wo     = (const float*)d_in[8];
  const float* qnw    = (const float*)d_in[9];
  const float* knw    = (const float*)d_in[10];
  float* out = (float*)d_out;
  char* ws = (char*)d_ws;
  bf16*  h_bf    = (bf16*)(ws + 0);          // 2048*3584*2   = 14,680,064
  bf16*  wqkv_bf = (bf16*)(ws + 14680064);   // 8192*3584*2   = 58,720,256
  bf16*  wo_bf   = (bf16*)(ws + 73400320);   // 3584*4096*2   = 29,360,128
  float* qkv     = (float*)(ws + 102760448); // 2048*8192*4   = 67,108,864
  bf16*  qb      = (bf16*)(ws + 169869312);  // 16*2048*256*2 = 16,777,216
  bf16*  kb      = (bf16*)(ws + 186646528);  // 8*2048*256*2  =  8,388,608
  bf16*  vtb     = (bf16*)(ws + 195035136);  // 8*256*2048*2  =  8,388,608
  bf16*  attnb   = (bf16*)(ws + 203423744);  // 2048*4096*2   = 16,777,216
  // split-K partials reuse the qkv region (dead after qk_norm_rope + v_transpose)
  float* part0   = (float*)(ws + 102760448);
  float* part1   = part0 + (size_t)2048 * 3584;

  cast3_kernel<<<2048, 256, 0, stream>>>(hidden, h_bf, 1835008,
                                         wqkv, wqkv_bf, 7340032,
                                         wo, wo_bf, 3670016);
  gemm_nt_8p<<<256, 512, 0, stream>>>(h_bf, wqkv_bf, qkv, 2048, 8192, 3584);
  qk_norm_rope<<<2048, 256, 0, stream>>>(qkv, cosb, sinb, qnw, knw, qb, kb);
  v_transpose<<<dim3(4, 32, 8), 256, 0, stream>>>(qkv, vtb);
  attn_kernel<<<dim3(16, 32), 512, 0, stream>>>(qb, kb, vtb, attnb);
  gemm_nt_8p_ks<<<224, 512, 0, stream>>>(attnb, wo_bf, part0, 2048, 3584, 2048, 4096);
  add2_kernel<<<2048, 256, 0, stream>>>(part0, part1, out, 1835008);
}